// Round 1
// 277.099 us; speedup vs baseline: 1.0650x; 1.0650x over previous
//
#include <hip/hip_runtime.h>
#include <hip/hip_bf16.h>
#include <stdint.h>
#include <stddef.h>

// Problem constants
#define BATCH   4096
#define INDIM   512
#define OUTDIM  512
#define NH      32
#define KKDIM   64                 // 2*NH k-values per input dim
#define INV2PI  0.15915494309189535f

// Main-kernel tiling: 256x256 block tile, 8 waves of 128x64 -> LDS reads
// drop from 30.5 to 22.9 B/KFLOP vs the old 128x256 / 64x64 arrangement.
#define BM       256
#define BN       256
#define THREADS  512
#define KSPLIT   8
#define DIMS_PER_WG (INDIM / KSPLIT)   // 64 input dims per workgroup
#define CHUNK_ELEMS (BN * KKDIM)       // 16384 bf16 = 32 KB per (colblock, dim) chunk

// LDS layout (bytes)
#define B_BYTES   32768                       // [256 col][64 kk] bf16, xor-swizzled
#define A_BYTES   (BM * 128)                  // [256 row][64 kk] bf16, xor-swizzled (32 KB)
#define OFF_A0    (2 * B_BYTES)               // 65536
#define OFF_X     (OFF_A0 + 2 * A_BYTES)      // 131072; 2 x-chunks of [8 dims][256 rows] f32
#define X_CHUNK_BYTES (8 * BM * 4)            // 8192
#define SMEM_BYTES (OFF_X + 2 * X_CHUNK_BYTES) // 147456 (fits 160 KiB, 1 block/CU)

typedef short  bhalf8  __attribute__((ext_vector_type(8)));  // 8 bf16 (4 VGPRs)
typedef float  vfloat4 __attribute__((ext_vector_type(4)));

__device__ __forceinline__ unsigned pack_bf16(float a, float b) {
    union { __hip_bfloat162 h2; unsigned u; } cv;
    cv.h2 = __float22bfloat162_rn(float2{a, b});   // cos in low half (kk even), sin in high
    return cv.u;
}

__device__ __forceinline__ void async_copy16(const void* gsrc, void* ldst) {
    __builtin_amdgcn_global_load_lds(
        (const __attribute__((address_space(1))) void*)(uintptr_t)gsrc,
        (__attribute__((address_space(3))) void*)(uint32_t)(uintptr_t)ldst,
        16, 0, 0);
}

// ---------------------------------------------------------------------------
// Prepass: fourier_coeffs fp32 [512,32,2,512] -> bf16 tiles in ws.
// Chunk (cb, i) is 32 KB: [col 0..255][kk 0..63] with 16B-unit swizzle
// pc = (kk>>3) ^ (col&7) baked in. LDS-transpose version: global loads AND
// stores fully coalesced (old version did 64 stride-2KB scalar loads/thread).
// ---------------------------------------------------------------------------
__global__ __launch_bounds__(256) void fkan_prepass(const float* __restrict__ coeffs,
                                                    unsigned short* __restrict__ Bt) {
    __shared__ float lds[64][260];   // pad 260: conflict-free f32x4 writes + scalar reads
    const int t  = threadIdx.x;
    const int cb = blockIdx.x & 1;
    const int i  = blockIdx.x >> 1;
    const float* __restrict__ src = coeffs + (size_t)i * (KKDIM * OUTDIM) + cb * BN;
    unsigned short* __restrict__ chunk = Bt + (size_t)(cb * INDIM + i) * CHUNK_ELEMS;
#pragma unroll
    for (int rd = 0; rd < 16; ++rd) {
        const int r  = rd * 4 + (t >> 6);       // each wave loads one kk-row, coalesced
        const int c4 = (t & 63) * 4;
        const float4 v = *(const float4*)(src + (size_t)r * OUTDIM + c4);
        *(float4*)&lds[r][c4] = v;
    }
    __syncthreads();
#pragma unroll
    for (int s = 0; s < 8; ++s) {
        const int unit = t + s * 256;          // 2048 16B-units per chunk
        const int col  = unit >> 3;
        const int pc   = unit & 7;             // physical 16B slot in this col's row
        const int kb   = (pc ^ (col & 7)) * 8; // logical kk base held in this slot
        uint4 o;
        o.x = pack_bf16(lds[kb + 0][col], lds[kb + 1][col]);
        o.y = pack_bf16(lds[kb + 2][col], lds[kb + 3][col]);
        o.z = pack_bf16(lds[kb + 4][col], lds[kb + 5][col]);
        o.w = pack_bf16(lds[kb + 6][col], lds[kb + 7][col]);
        ((uint4*)chunk)[unit] = o;             // lane-contiguous coalesced store
    }
}

// out[b,o] = bias[o]
__global__ __launch_bounds__(256) void fkan_bias_init(const float* __restrict__ bias,
                                                      float* __restrict__ out) {
    const int idx = blockIdx.x * 256 + threadIdx.x;       // 524288 float4s
    ((float4*)out)[idx] = ((const float4*)bias)[idx & 127];
}

// ---------------------------------------------------------------------------
// Main fused kernel helpers
// ---------------------------------------------------------------------------
__device__ __forceinline__ void stage_B(const unsigned short* __restrict__ Bt, char* smem,
                                        int cb, int dim_global, int parity, int t) {
    const char* chunk = (const char*)(Bt + (size_t)(cb * INDIM + dim_global) * CHUNK_ELEMS);
    char* bdst = smem + parity * B_BYTES;
#pragma unroll
    for (int s = 0; s < 4; ++s) {
        const int unit = t + s * 512;
        async_copy16(chunk + unit * 16, bdst + unit * 16);  // dest = wave base + lane*16
    }
}

__device__ __forceinline__ void stage_x(const float* __restrict__ x, char* smem,
                                        int rowbase, int dimbase, int cn, int t) {
    const int r  = t >> 1;                     // 256 rows, 2 threads/row
    const int d0 = (t & 1) * 4;
    const float4 xv = *(const float4*)(x + (size_t)(rowbase + r) * INDIM + dimbase + cn * 8 + d0);
    float* xr = (float*)(smem + OFF_X + (cn & 1) * X_CHUNK_BYTES);  // [8][256] f32
    xr[(d0 + 0) * BM + r] = xv.x * INV2PI;     // store revolutions; banks = r mod 32 -> 2-way
    xr[(d0 + 1) * BM + r] = xv.y * INV2PI;
    xr[(d0 + 2) * BM + r] = xv.z * INV2PI;
    xr[(d0 + 3) * BM + r] = xv.w * INV2PI;
}

// Compute cos/sin(k*x) for 16 harmonics via complex recurrence, pack bf16 pairs
// into A_lds[row][kk] (kk = 2*(k-1)+{0:cos,1:sin}), 16B-unit xor swizzle
// phys = unit ^ (row&7): both these writes and the MFMA av reads are
// bank-uniform (replaces the old pad-72 layout whose writes were 8-way).
__device__ __forceinline__ void do_trig(char* smem, int dim_local, int parity, int trow, int tq) {
    const float rv = ((const float*)(smem + OFF_X + ((dim_local >> 3) & 1) * X_CHUNK_BYTES))
                     [(dim_local & 7) * BM + trow];
    const float cd = __builtin_amdgcn_cosf(rv);   // step e^{i*x} (revolution domain)
    const float sd = __builtin_amdgcn_sinf(rv);
    const float a0 = (float)(tq * 16 + 1) * rv;   // base harmonic k0 = tq*16+1 (|k0*rv| < old max)
    float c = __builtin_amdgcn_cosf(a0);
    float s = __builtin_amdgcn_sinf(a0);
    unsigned pk[16];
    pk[0] = pack_bf16(c, s);
#pragma unroll
    for (int j = 1; j < 16; ++j) {
        const float nc = c * cd - s * sd;
        const float ns = s * cd + c * sd;
        c = nc; s = ns;
        pk[j] = pack_bf16(c, s);
    }
    uint4* abase = (uint4*)(smem + OFF_A0 + parity * A_BYTES + trow * 128);
    const int sw = trow & 7;
    uint4 w0; w0.x = pk[0];  w0.y = pk[1];  w0.z = pk[2];  w0.w = pk[3];
    uint4 w1; w1.x = pk[4];  w1.y = pk[5];  w1.z = pk[6];  w1.w = pk[7];
    uint4 w2; w2.x = pk[8];  w2.y = pk[9];  w2.z = pk[10]; w2.w = pk[11];
    uint4 w3; w3.x = pk[12]; w3.y = pk[13]; w3.z = pk[14]; w3.w = pk[15];
    abase[(tq * 4 + 0) ^ sw] = w0;
    abase[(tq * 4 + 1) ^ sw] = w1;
    abase[(tq * 4 + 2) ^ sw] = w2;
    abase[(tq * 4 + 3) ^ sw] = w3;
}

// ---------------------------------------------------------------------------
// Main kernel: grid 256 (= 16 rowblocks x 2 colblocks x 8 ksplits), 512 thr.
// blockIdx&15 -> (colblock, ksplit) group; members stride 16 so every member
// of a group lands on one XCD (round-robin %8), 2 groups/XCD x 2MB bf16
// B-chunk = 4MB, exactly that XCD's L2.
// ---------------------------------------------------------------------------
__global__ __launch_bounds__(THREADS, 2) void fkan_main(const float* __restrict__ x,
                                                        const unsigned short* __restrict__ Bt,
                                                        float* __restrict__ out) {
    __shared__ char smem[SMEM_BYTES];
    const int t      = threadIdx.x;
    const int grp    = blockIdx.x & 15;
    const int member = blockIdx.x >> 4;
    const int cb      = grp & 1;
    const int kq      = grp >> 1;
    const int rowbase = member * BM;
    const int colbase = cb * BN;
    const int dimbase = kq * DIMS_PER_WG;

    const int lane = t & 63;
    const int w    = t >> 6;
    const int wr   = w >> 2;       // wave grid 2 rows x 4 cols; wave tile 128x64
    const int wc   = w & 3;
    const int fr   = lane & 15;    // row/col within 16x16 tile
    const int fq   = lane >> 4;    // quad -> k-chunk of 8
    const int fx   = lane & 7;     // xor swizzle key (== row&7 / col&7, tiles 16-aligned)

    const int trow = t >> 1;       // trig: 2 threads per row, 16 harmonics each
    const int tq   = t & 1;

    vfloat4 acc[8][4];
#pragma unroll
    for (int a = 0; a < 8; ++a)
#pragma unroll
        for (int b = 0; b < 4; ++b) acc[a][b] = (vfloat4)0.0f;

    // Prologue: x chunk 0, then B+A for dim 0 into buffer 0.
    stage_x(x, smem, rowbase, dimbase, 0, t);
    __syncthreads();
    stage_B(Bt, smem, cb, dimbase + 0, 0, t);
    do_trig(smem, 0, 0, trow, tq);
    __syncthreads();

#pragma unroll 2
    for (int it = 0; it < DIMS_PER_WG; ++it) {
        const int p    = it & 1;
        const int inxt = it + 1;
        if (inxt < DIMS_PER_WG) {
            stage_B(Bt, smem, cb, dimbase + inxt, inxt & 1, t);   // async, fills 1-p
            if ((it & 7) == 0) {
                const int cn = (it >> 3) + 1;                     // stage x one chunk ahead
                if (cn < 8) stage_x(x, smem, rowbase, dimbase, cn, t);
            }
            do_trig(smem, inxt, inxt & 1, trow, tq);              // VALU, overlaps MFMA
        }
        // Compute on buffer p
        {
            const char* Ab = smem + OFF_A0 + p * A_BYTES;
            const char* Bb = smem + p * B_BYTES;
#pragma unroll
            for (int ks = 0; ks < 2; ++ks) {
                bhalf8 bv[4];
#pragma unroll
                for (int ct = 0; ct < 4; ++ct)
                    bv[ct] = *(const bhalf8*)(Bb + (wc * 64 + ct * 16 + fr) * 128
                                                 + (((ks * 4 + fq) ^ fx) * 16));
#pragma unroll
                for (int rt = 0; rt < 8; ++rt) {
                    const bhalf8 av = *(const bhalf8*)(Ab + (wr * 128 + rt * 16 + fr) * 128
                                                          + (((ks * 4 + fq) ^ fx) * 16));
#pragma unroll
                    for (int ct = 0; ct < 4; ++ct)
                        acc[rt][ct] = __builtin_amdgcn_mfma_f32_16x16x32_bf16(
                            av, bv[ct], acc[rt][ct], 0, 0, 0);
                }
            }
        }
        __syncthreads();
    }

    // Epilogue: C/D layout col=lane&15, row=quad*4+reg (m89). KSPLIT partials via atomics.
#pragma unroll
    for (int rt = 0; rt < 8; ++rt) {
#pragma unroll
        for (int ct = 0; ct < 4; ++ct) {
            const int col  = colbase + wc * 64 + ct * 16 + fr;
            const int row0 = rowbase + wr * 128 + rt * 16 + fq * 4;
#pragma unroll
            for (int r = 0; r < 4; ++r)
                atomicAdd(out + (size_t)(row0 + r) * OUTDIM + col, acc[rt][ct][r]);
        }
    }
}

// ---------------------------------------------------------------------------
// Fallback (only if ws too small for the 32MB bf16 B): slow but correct fp32.
// ---------------------------------------------------------------------------
__global__ __launch_bounds__(256) void fkan_naive(const float* __restrict__ x,
                                                  const float* __restrict__ coeffs,
                                                  const float* __restrict__ bias,
                                                  float* __restrict__ out) {
    const int b = blockIdx.x >> 1;
    const int o = ((blockIdx.x & 1) << 8) + threadIdx.x;
    float acc = bias[o];
    const float* xrow = x + (size_t)b * INDIM;
    for (int i = 0; i < INDIM; ++i) {
        const float rv = xrow[i] * INV2PI;
        const float cd = __builtin_amdgcn_cosf(rv);
        const float sd = __builtin_amdgcn_sinf(rv);
        float c = cd, s = sd;
        const float* cp = coeffs + (size_t)i * (KKDIM * OUTDIM) + o;
#pragma unroll 4
        for (int g = 0; g < NH; ++g) {
            acc += c * cp[g * 2 * OUTDIM] + s * cp[(g * 2 + 1) * OUTDIM];
            const float nc = c * cd - s * sd;
            const float ns = s * cd + c * sd;
            c = nc; s = ns;
        }
    }
    out[(size_t)b * OUTDIM + o] = acc;
}

extern "C" void kernel_launch(void* const* d_in, const int* in_sizes, int n_in,
                              void* d_out, int out_size, void* d_ws, size_t ws_size,
                              hipStream_t stream) {
    (void)in_sizes; (void)n_in; (void)out_size;
    const float* x      = (const float*)d_in[0];
    const float* coeffs = (const float*)d_in[1];
    const float* bias   = (const float*)d_in[2];
    float* out          = (float*)d_out;

    const size_t bt_bytes = (size_t)2 * INDIM * CHUNK_ELEMS * sizeof(unsigned short); // 32 MiB
    if (ws_size >= bt_bytes) {
        unsigned short* Bt = (unsigned short*)d_ws;
        fkan_prepass<<<2 * INDIM, 256, 0, stream>>>(coeffs, Bt);          // 1024 blocks
        fkan_bias_init<<<(BATCH * OUTDIM) / (4 * 256), 256, 0, stream>>>(bias, out);
        fkan_main<<<(BATCH / BM) * 2 * KSPLIT, THREADS, 0, stream>>>(x, Bt, out);  // 256 blocks
    } else {
        fkan_naive<<<BATCH * 2, 256, 0, stream>>>(x, coeffs, bias, out);
    }
}